// Round 10
// baseline (218.962 us; speedup 1.0000x reference)
//
#include <hip/hip_runtime.h>
#include <hip/hip_fp16.h>

// imgs (8,3,1024,1024) fp32, z (1e6,2) fp32 -> out (8,2) fp32.
// R10: gather-dual linear reformulation (R8/R9) with barrier-free precompute.
//   gc0(point) = Dy[yg][xg] + u*M[yg][xg],  gc1 = Dx[yg][xg] + v*M[yg][xg]
// with S_b = sum_c imgs[b,c], Dy=S(y+1,x)-S(y,x), Dx=S(y,x+1)-S(y,x),
// M = S(y+1,x+1)-S(y,x+1)-S(y+1,x)+S(y,x).
// T record per pixel: 64 B = uint4[4]: [0]=Dy(8 half), [1]=Dx, [2]=M, [3]=pad.
// R9 lessons: LDS-staged write-out gives exactly 64 MB writes (keep, incl. the
// pad write -> full lines); precompute was barrier/latency-bound (16 barriers +
// serial thread-0 edge loads; VALUBusy 5%, 3 TB/s). R10: each thread loads S at
// x AND x+1 redundantly (96 independent loads, x+1 hits same L1 lines) -> no
// S-staging, 2 barriers total.

#define NYX 1024
#define NPIX (NYX * NYX)
#define BATCH 8
#define CH 3
#define GB 2048                                  // gather blocks
#define PART_OFF ((size_t)NPIX * 64)             // 64 MB of T, then partials

__device__ __forceinline__ unsigned pk2(float a, float b) {
    __half2 h = __floats2half2_rn(a, b);
    return *(unsigned*)&h;
}

__global__ __launch_bounds__(256) void precompute_kernel(
    const float* __restrict__ imgs, uint4* __restrict__ T)
{
    int bid = blockIdx.x;
    int y   = bid >> 2;                  // 0..1023
    int x0  = (bid & 3) << 8;            // 0,256,512,768
    int t   = threadIdx.x;
    int x   = x0 + t;
    int xp  = min(x + 1, NYX - 1);       // x=1023 record garbage, never read
    int yp  = min(y + 1, NYX - 1);       // y=1023 record garbage, never read

    size_t r0 = (size_t)y  * NYX;
    size_t r1 = (size_t)yp * NYX;

    __shared__ uint4 stage[1024];        // 256 records x 64 B = 16 KB

    float c00[BATCH], c01[BATCH], c10[BATCH], c11[BATCH];
#pragma unroll
    for (int b = 0; b < BATCH; ++b) { c00[b]=0.f; c01[b]=0.f; c10[b]=0.f; c11[b]=0.f; }

#pragma unroll
    for (int b = 0; b < BATCH; ++b) {
#pragma unroll
        for (int c = 0; c < CH; ++c) {
            const float* pl = imgs + (size_t)(b * CH + c) * NPIX;
            c00[b] += pl[r0 + x];
            c01[b] += pl[r0 + xp];
            c10[b] += pl[r1 + x];
            c11[b] += pl[r1 + xp];
        }
    }

    float Dy[BATCH], Dx[BATCH], Mm[BATCH];
#pragma unroll
    for (int b = 0; b < BATCH; ++b) {
        Dy[b] = c10[b] - c00[b];
        Dx[b] = c01[b] - c00[b];
        Mm[b] = (c11[b] - c01[b]) - Dy[b];
    }

    stage[t * 4 + 0] = make_uint4(pk2(Dy[0], Dy[1]), pk2(Dy[2], Dy[3]),
                                  pk2(Dy[4], Dy[5]), pk2(Dy[6], Dy[7]));
    stage[t * 4 + 1] = make_uint4(pk2(Dx[0], Dx[1]), pk2(Dx[2], Dx[3]),
                                  pk2(Dx[4], Dx[5]), pk2(Dx[6], Dx[7]));
    stage[t * 4 + 2] = make_uint4(pk2(Mm[0], Mm[1]), pk2(Mm[2], Mm[3]),
                                  pk2(Mm[4], Mm[5]), pk2(Mm[6], Mm[7]));
    stage[t * 4 + 3] = make_uint4(0u, 0u, 0u, 0u);
    __syncthreads();

    // coalesced copy-out: 1024 consecutive uint4 (16 KB window, full lines)
    size_t base4 = ((size_t)y * NYX + x0) * 4;
#pragma unroll
    for (int i = 0; i < 4; ++i)
        T[base4 + i * 256 + t] = stage[i * 256 + t];
}

__global__ __launch_bounds__(256) void gather_kernel(
    const float* __restrict__ z, const uint4* __restrict__ T,
    float* __restrict__ partials, int npts)
{
    float acc0[BATCH];
    float acc1[BATCH];
#pragma unroll
    for (int b = 0; b < BATCH; ++b) { acc0[b] = 0.0f; acc1[b] = 0.0f; }

    int stride = gridDim.x * blockDim.x;
    for (int p = blockIdx.x * blockDim.x + threadIdx.x; p < npts; p += stride) {
        float2 zz = ((const float2*)z)[p];
        float x0y = zz.x * (float)(NYX - 1);
        float x0x = zz.y * (float)(NYX - 1);
        bool oob = (x0y < 0.0f) || (x0y > (float)(NYX - 1)) ||
                   (x0x < 0.0f) || (x0x > (float)(NYX - 1));
        if (oob) continue;
        int yg = min((int)floorf(x0y), NYX - 2);
        int xg = min((int)floorf(x0x), NYX - 2);
        float u = x0x - (float)xg;   // [0,1)
        float v = x0y - (float)yg;
        const uint4* t4 = T + ((size_t)yg * NYX + xg) * 4;
        uint4 qDy = t4[0];
        uint4 qDx = t4[1];
        uint4 qM  = t4[2];
        const __half2* hDy = (const __half2*)&qDy;
        const __half2* hDx = (const __half2*)&qDx;
        const __half2* hM  = (const __half2*)&qM;
#pragma unroll
        for (int j = 0; j < 4; ++j) {
            float2 dy = __half22float2(hDy[j]);
            float2 dx = __half22float2(hDx[j]);
            float2 m  = __half22float2(hM[j]);
            acc0[2 * j + 0] += fmaf(u, m.x, dy.x);
            acc0[2 * j + 1] += fmaf(u, m.y, dy.y);
            acc1[2 * j + 0] += fmaf(v, m.x, dx.x);
            acc1[2 * j + 1] += fmaf(v, m.y, dx.y);
        }
    }

#pragma unroll
    for (int b = 0; b < BATCH; ++b) {
#pragma unroll
        for (int off = 32; off > 0; off >>= 1) {
            acc0[b] += __shfl_down(acc0[b], off, 64);
            acc1[b] += __shfl_down(acc1[b], off, 64);
        }
    }

    __shared__ float sred[4][16];
    int lane = threadIdx.x & 63;
    int wave = threadIdx.x >> 6;
    if (lane == 0) {
#pragma unroll
        for (int b = 0; b < BATCH; ++b) {
            sred[wave][2 * b + 0] = acc0[b];
            sred[wave][2 * b + 1] = acc1[b];
        }
    }
    __syncthreads();
    if (threadIdx.x < 16) {
        float s = sred[0][threadIdx.x] + sred[1][threadIdx.x] +
                  sred[2][threadIdx.x] + sred[3][threadIdx.x];
        partials[blockIdx.x * 16 + threadIdx.x] = s;
    }
}

__global__ __launch_bounds__(256) void final_reduce_kernel(
    const float* __restrict__ partials, float* __restrict__ out)
{
    int j = threadIdx.x & 15;
    int chunk = threadIdx.x >> 4;
    float s = 0.0f;
    int r0 = chunk * (GB / 16);
    for (int r = r0; r < r0 + (GB / 16); ++r)
        s += partials[r * 16 + j];
    __shared__ float tmp[256];
    tmp[threadIdx.x] = s;
    __syncthreads();
    if (threadIdx.x < 16) {
        float t = 0.0f;
#pragma unroll
        for (int c = 0; c < 16; ++c) t += tmp[c * 16 + threadIdx.x];
        out[threadIdx.x] = t;
    }
}

// ---- fallback (round-1 unsorted path) if ws is too small ----
__global__ void zero_out_kernel(float* __restrict__ out) {
    int i = threadIdx.x;
    if (i < 16) out[i] = 0.0f;
}

__global__ __launch_bounds__(256) void interp_grad_kernel(
    const float* __restrict__ imgs, const float* __restrict__ z,
    float* __restrict__ out, int npts)
{
    int p = blockIdx.x * blockDim.x + threadIdx.x;
    float acc0[BATCH];
    float acc1[BATCH];
#pragma unroll
    for (int b = 0; b < BATCH; ++b) { acc0[b] = 0.0f; acc1[b] = 0.0f; }
    if (p < npts) {
        float2 zz = ((const float2*)z)[p];
        float x0y = zz.x * (float)(NYX - 1);
        float x0x = zz.y * (float)(NYX - 1);
        bool oob = (x0y < 0.0f) || (x0y > (float)(NYX - 1)) ||
                   (x0x < 0.0f) || (x0x > (float)(NYX - 1));
        if (!oob) {
            int yg = min((int)floorf(x0y), NYX - 2);
            int xg = min((int)floorf(x0x), NYX - 2);
            float fy = (float)yg - x0y;
            float fx = (float)xg - x0x;
            const float* base = imgs + (size_t)yg * NYX + xg;
#pragma unroll
            for (int b = 0; b < BATCH; ++b) {
#pragma unroll
                for (int c = 0; c < CH; ++c) {
                    const float* pl = base + (size_t)(b * CH + c) * (size_t)NPIX;
                    float g00 = pl[0];
                    float g01 = pl[1];
                    float g10 = pl[NYX];
                    float g11 = pl[NYX + 1];
                    float a1 = g10 - g00;
                    float a2 = g11 - g01;
                    float a3 = g01 - g00;
                    float d  = a1 - a2;
                    acc0[b] += d * fx + a1;
                    acc1[b] += d * fy + a3;
                }
            }
        }
    }
#pragma unroll
    for (int b = 0; b < BATCH; ++b) {
#pragma unroll
        for (int off = 32; off > 0; off >>= 1) {
            acc0[b] += __shfl_down(acc0[b], off, 64);
            acc1[b] += __shfl_down(acc1[b], off, 64);
        }
    }
    __shared__ float sred[4][16];
    int lane = threadIdx.x & 63;
    int wave = threadIdx.x >> 6;
    if (lane == 0) {
#pragma unroll
        for (int b = 0; b < BATCH; ++b) {
            sred[wave][2 * b + 0] = acc0[b];
            sred[wave][2 * b + 1] = acc1[b];
        }
    }
    __syncthreads();
    if (threadIdx.x < 16) {
        float s = sred[0][threadIdx.x] + sred[1][threadIdx.x] +
                  sred[2][threadIdx.x] + sred[3][threadIdx.x];
        atomicAdd(&out[threadIdx.x], s);
    }
}

extern "C" void kernel_launch(void* const* d_in, const int* in_sizes, int n_in,
                              void* d_out, int out_size, void* d_ws, size_t ws_size,
                              hipStream_t stream) {
    const float* imgs = (const float*)d_in[0];
    const float* z    = (const float*)d_in[1];
    float* out        = (float*)d_out;
    int npts = in_sizes[1] / 2;

    size_t ws_need = PART_OFF + (size_t)GB * 16 * sizeof(float);  // ~64.1 MB

    if (ws_size < ws_need) {
        int blocks = (npts + 255) / 256;
        zero_out_kernel<<<1, 64, 0, stream>>>(out);
        interp_grad_kernel<<<blocks, 256, 0, stream>>>(imgs, z, out, npts);
        return;
    }

    uint4* T        = (uint4*)d_ws;
    float* partials = (float*)((char*)d_ws + PART_OFF);

    precompute_kernel<<<NYX * 4, 256, 0, stream>>>(imgs, T);
    gather_kernel<<<GB, 256, 0, stream>>>(z, T, partials, npts);
    final_reduce_kernel<<<1, 256, 0, stream>>>(partials, out);
}

// Round 11
// 198.000 us; speedup vs baseline: 1.1059x; 1.1059x over previous
//
#include <hip/hip_runtime.h>
#include <hip/hip_fp16.h>

// imgs (8,3,1024,1024) fp32, z (1e6,2) fp32 -> out (8,2) fp32.
// R11: gather-dual linear reformulation (R8-R10).
//   gc0(point) = Dy[yg][xg] + u*M[yg][xg],  gc1 = Dx[yg][xg] + v*M[yg][xg]
// T record per pixel: 64 B = uint4[4]: [0]=Dy(8 half), [1]=Dx, [2]=M, [3]=pad.
// R10 lesson: precompute stuck at 3 TB/s with VGPR=32 -> ~1 outstanding
// load/wave (compiler folds each load straight into accumulator). R11: group
// threads (4 groups x 64 lanes, 2 batches/group), 12 independent float4 loads
// into distinct regs, __launch_bounds__(256,4) for a 128-VGPR budget, S rows
// exchanged via LDS. Gather: GB back to 1024 (2048 regressed), 2 pts/iter with
// all 6 record loads issued before the math, branchless oob.

#define NYX 1024
#define NPIX (NYX * NYX)
#define BATCH 8
#define CH 3
#define GB 1024                                  // gather blocks
#define SROW 260                                 // LDS row stride (16B-aligned)
#define PART_OFF ((size_t)NPIX * 64)             // 64 MB of T, then partials

__device__ __forceinline__ unsigned pk2(float a, float b) {
    __half2 h = __floats2half2_rn(a, b);
    return *(unsigned*)&h;
}

__device__ __forceinline__ float4 add4(float4 a, float4 b, float4 c) {
    return make_float4(a.x + b.x + c.x, a.y + b.y + c.y,
                       a.z + b.z + c.z, a.w + b.w + c.w);
}

__global__ __launch_bounds__(256, 4) void precompute_kernel(
    const float* __restrict__ imgs, uint4* __restrict__ T)
{
    int bid  = blockIdx.x;
    int y    = bid >> 2;                 // 0..1023
    int x0   = (bid & 3) << 8;           // 0,256,512,768
    int t    = threadIdx.x;
    int lane = t & 63;
    int g    = t >> 6;                   // group 0..3 -> batches 2g,2g+1
    int yp   = min(y + 1, NYX - 1);      // y=1023 records garbage, never read
    int xe   = min(x0 + 256, NYX - 1);   // strip-edge column (x=1023 unread)

    size_t q0 = (size_t)y  * NYX + x0;
    size_t q1 = (size_t)yp * NYX + x0;

    __shared__ float sS[BATCH * 2 * SROW];   // 16640 B: S_b rows y,y+1 + edge
    __shared__ uint4 stage[1024];            // 16384 B: 256 records x 64 B

    // 12 independent float4 loads (2 b x 3 c x 2 rows), distinct registers
    float4 v[12];
#pragma unroll
    for (int bl = 0; bl < 2; ++bl) {
        int b = 2 * g + bl;
#pragma unroll
        for (int c = 0; c < CH; ++c) {
            const float* pl = imgs + (size_t)(b * CH + c) * NPIX;
            v[bl * 6 + c * 2 + 0] = ((const float4*)(pl + q0))[lane];
            v[bl * 6 + c * 2 + 1] = ((const float4*)(pl + q1))[lane];
        }
    }
    float edge[4] = {0.f, 0.f, 0.f, 0.f};
    if (lane == 63) {
#pragma unroll
        for (int bl = 0; bl < 2; ++bl) {
            int b = 2 * g + bl;
#pragma unroll
            for (int c = 0; c < CH; ++c) {
                const float* pl = imgs + (size_t)(b * CH + c) * NPIX;
                edge[bl * 2 + 0] += pl[(size_t)y  * NYX + xe];
                edge[bl * 2 + 1] += pl[(size_t)yp * NYX + xe];
            }
        }
    }

#pragma unroll
    for (int bl = 0; bl < 2; ++bl) {
        int b = 2 * g + bl;
        float4 s0 = add4(v[bl * 6 + 0], v[bl * 6 + 2], v[bl * 6 + 4]);
        float4 s1 = add4(v[bl * 6 + 1], v[bl * 6 + 3], v[bl * 6 + 5]);
        *(float4*)&sS[(b * 2 + 0) * SROW + 4 * lane] = s0;
        *(float4*)&sS[(b * 2 + 1) * SROW + 4 * lane] = s1;
        if (lane == 63) {
            sS[(b * 2 + 0) * SROW + 256] = edge[bl * 2 + 0];
            sS[(b * 2 + 1) * SROW + 256] = edge[bl * 2 + 1];
        }
    }
    __syncthreads();

    // per-thread record for pixel x0+t
    float Dy[BATCH], Dx[BATCH], Mm[BATCH];
#pragma unroll
    for (int b = 0; b < BATCH; ++b) {
        float c00 = sS[(b * 2 + 0) * SROW + t];
        float c01 = sS[(b * 2 + 0) * SROW + t + 1];
        float c10 = sS[(b * 2 + 1) * SROW + t];
        float c11 = sS[(b * 2 + 1) * SROW + t + 1];
        Dy[b] = c10 - c00;
        Dx[b] = c01 - c00;
        Mm[b] = (c11 - c01) - Dy[b];
    }

    stage[t * 4 + 0] = make_uint4(pk2(Dy[0], Dy[1]), pk2(Dy[2], Dy[3]),
                                  pk2(Dy[4], Dy[5]), pk2(Dy[6], Dy[7]));
    stage[t * 4 + 1] = make_uint4(pk2(Dx[0], Dx[1]), pk2(Dx[2], Dx[3]),
                                  pk2(Dx[4], Dx[5]), pk2(Dx[6], Dx[7]));
    stage[t * 4 + 2] = make_uint4(pk2(Mm[0], Mm[1]), pk2(Mm[2], Mm[3]),
                                  pk2(Mm[4], Mm[5]), pk2(Mm[6], Mm[7]));
    stage[t * 4 + 3] = make_uint4(0u, 0u, 0u, 0u);
    __syncthreads();

    // coalesced copy-out: 1024 consecutive uint4 (16 KB window, full lines)
    size_t base4 = ((size_t)y * NYX + x0) * 4;
#pragma unroll
    for (int i = 0; i < 4; ++i)
        T[base4 + i * 256 + t] = stage[i * 256 + t];
}

struct PtSetup {
    const uint4* t4;
    float u, v, s;
};

__device__ __forceinline__ PtSetup setup_pt(float zy, float zx,
                                            const uint4* __restrict__ T) {
    PtSetup r;
    float x0y = zy * (float)(NYX - 1);
    float x0x = zx * (float)(NYX - 1);
    bool oob = (x0y < 0.0f) || (x0y > (float)(NYX - 1)) ||
               (x0x < 0.0f) || (x0x > (float)(NYX - 1));
    float cy = fminf(fmaxf(x0y, 0.0f), (float)(NYX - 1));
    float cx = fminf(fmaxf(x0x, 0.0f), (float)(NYX - 1));
    int yg = min((int)cy, NYX - 2);
    int xg = min((int)cx, NYX - 2);
    r.u = cx - (float)xg;
    r.v = cy - (float)yg;
    r.s = oob ? 0.0f : 1.0f;
    r.t4 = T + ((size_t)yg * NYX + xg) * 4;
    return r;
}

__global__ __launch_bounds__(256, 4) void gather_kernel(
    const float* __restrict__ z, const uint4* __restrict__ T,
    float* __restrict__ partials, int npts)
{
    float acc0[BATCH];
    float acc1[BATCH];
#pragma unroll
    for (int b = 0; b < BATCH; ++b) { acc0[b] = 0.0f; acc1[b] = 0.0f; }

    const float4* z4 = (const float4*)z;
    int npairs = npts >> 1;
    int stride = gridDim.x * blockDim.x;

    for (int i = blockIdx.x * blockDim.x + threadIdx.x; i < npairs; i += stride) {
        float4 zz = z4[i];
        PtSetup A = setup_pt(zz.x, zz.y, T);
        PtSetup B = setup_pt(zz.z, zz.w, T);
        // issue all 6 line loads before the math
        uint4 aDy = A.t4[0], aDx = A.t4[1], aM = A.t4[2];
        uint4 bDy = B.t4[0], bDx = B.t4[1], bM = B.t4[2];
        const __half2* haDy = (const __half2*)&aDy;
        const __half2* haDx = (const __half2*)&aDx;
        const __half2* haM  = (const __half2*)&aM;
        const __half2* hbDy = (const __half2*)&bDy;
        const __half2* hbDx = (const __half2*)&bDx;
        const __half2* hbM  = (const __half2*)&bM;
#pragma unroll
        for (int j = 0; j < 4; ++j) {
            float2 dy = __half22float2(haDy[j]);
            float2 dx = __half22float2(haDx[j]);
            float2 m  = __half22float2(haM[j]);
            acc0[2 * j + 0] += A.s * fmaf(A.u, m.x, dy.x);
            acc0[2 * j + 1] += A.s * fmaf(A.u, m.y, dy.y);
            acc1[2 * j + 0] += A.s * fmaf(A.v, m.x, dx.x);
            acc1[2 * j + 1] += A.s * fmaf(A.v, m.y, dx.y);
            float2 ey = __half22float2(hbDy[j]);
            float2 ex = __half22float2(hbDx[j]);
            float2 em = __half22float2(hbM[j]);
            acc0[2 * j + 0] += B.s * fmaf(B.u, em.x, ey.x);
            acc0[2 * j + 1] += B.s * fmaf(B.u, em.y, ey.y);
            acc1[2 * j + 0] += B.s * fmaf(B.v, em.x, ex.x);
            acc1[2 * j + 1] += B.s * fmaf(B.v, em.y, ex.y);
        }
    }

    // odd-npts tail (not taken for npts = 1e6)
    if ((npts & 1) && blockIdx.x == 0 && threadIdx.x == 0) {
        float zy = z[2 * (npts - 1)], zx = z[2 * (npts - 1) + 1];
        PtSetup A = setup_pt(zy, zx, T);
        uint4 aDy = A.t4[0], aDx = A.t4[1], aM = A.t4[2];
        const __half2* hDy = (const __half2*)&aDy;
        const __half2* hDx = (const __half2*)&aDx;
        const __half2* hM  = (const __half2*)&aM;
#pragma unroll
        for (int j = 0; j < 4; ++j) {
            float2 dy = __half22float2(hDy[j]);
            float2 dx = __half22float2(hDx[j]);
            float2 m  = __half22float2(hM[j]);
            acc0[2 * j + 0] += A.s * fmaf(A.u, m.x, dy.x);
            acc0[2 * j + 1] += A.s * fmaf(A.u, m.y, dy.y);
            acc1[2 * j + 0] += A.s * fmaf(A.v, m.x, dx.x);
            acc1[2 * j + 1] += A.s * fmaf(A.v, m.y, dx.y);
        }
    }

#pragma unroll
    for (int b = 0; b < BATCH; ++b) {
#pragma unroll
        for (int off = 32; off > 0; off >>= 1) {
            acc0[b] += __shfl_down(acc0[b], off, 64);
            acc1[b] += __shfl_down(acc1[b], off, 64);
        }
    }

    __shared__ float sred[4][16];
    int lane = threadIdx.x & 63;
    int wave = threadIdx.x >> 6;
    if (lane == 0) {
#pragma unroll
        for (int b = 0; b < BATCH; ++b) {
            sred[wave][2 * b + 0] = acc0[b];
            sred[wave][2 * b + 1] = acc1[b];
        }
    }
    __syncthreads();
    if (threadIdx.x < 16) {
        float s = sred[0][threadIdx.x] + sred[1][threadIdx.x] +
                  sred[2][threadIdx.x] + sred[3][threadIdx.x];
        partials[blockIdx.x * 16 + threadIdx.x] = s;
    }
}

__global__ __launch_bounds__(256) void final_reduce_kernel(
    const float* __restrict__ partials, float* __restrict__ out)
{
    int j = threadIdx.x & 15;
    int chunk = threadIdx.x >> 4;
    float s = 0.0f;
    int r0 = chunk * (GB / 16);
    for (int r = r0; r < r0 + (GB / 16); ++r)
        s += partials[r * 16 + j];
    __shared__ float tmp[256];
    tmp[threadIdx.x] = s;
    __syncthreads();
    if (threadIdx.x < 16) {
        float t = 0.0f;
#pragma unroll
        for (int c = 0; c < 16; ++c) t += tmp[c * 16 + threadIdx.x];
        out[threadIdx.x] = t;
    }
}

// ---- fallback (round-1 unsorted path) if ws is too small ----
__global__ void zero_out_kernel(float* __restrict__ out) {
    int i = threadIdx.x;
    if (i < 16) out[i] = 0.0f;
}

__global__ __launch_bounds__(256) void interp_grad_kernel(
    const float* __restrict__ imgs, const float* __restrict__ z,
    float* __restrict__ out, int npts)
{
    int p = blockIdx.x * blockDim.x + threadIdx.x;
    float acc0[BATCH];
    float acc1[BATCH];
#pragma unroll
    for (int b = 0; b < BATCH; ++b) { acc0[b] = 0.0f; acc1[b] = 0.0f; }
    if (p < npts) {
        float2 zz = ((const float2*)z)[p];
        float x0y = zz.x * (float)(NYX - 1);
        float x0x = zz.y * (float)(NYX - 1);
        bool oob = (x0y < 0.0f) || (x0y > (float)(NYX - 1)) ||
                   (x0x < 0.0f) || (x0x > (float)(NYX - 1));
        if (!oob) {
            int yg = min((int)floorf(x0y), NYX - 2);
            int xg = min((int)floorf(x0x), NYX - 2);
            float fy = (float)yg - x0y;
            float fx = (float)xg - x0x;
            const float* base = imgs + (size_t)yg * NYX + xg;
#pragma unroll
            for (int b = 0; b < BATCH; ++b) {
#pragma unroll
                for (int c = 0; c < CH; ++c) {
                    const float* pl = base + (size_t)(b * CH + c) * (size_t)NPIX;
                    float g00 = pl[0];
                    float g01 = pl[1];
                    float g10 = pl[NYX];
                    float g11 = pl[NYX + 1];
                    float a1 = g10 - g00;
                    float a2 = g11 - g01;
                    float a3 = g01 - g00;
                    float d  = a1 - a2;
                    acc0[b] += d * fx + a1;
                    acc1[b] += d * fy + a3;
                }
            }
        }
    }
#pragma unroll
    for (int b = 0; b < BATCH; ++b) {
#pragma unroll
        for (int off = 32; off > 0; off >>= 1) {
            acc0[b] += __shfl_down(acc0[b], off, 64);
            acc1[b] += __shfl_down(acc1[b], off, 64);
        }
    }
    __shared__ float sred[4][16];
    int lane = threadIdx.x & 63;
    int wave = threadIdx.x >> 6;
    if (lane == 0) {
#pragma unroll
        for (int b = 0; b < BATCH; ++b) {
            sred[wave][2 * b + 0] = acc0[b];
            sred[wave][2 * b + 1] = acc1[b];
        }
    }
    __syncthreads();
    if (threadIdx.x < 16) {
        float s = sred[0][threadIdx.x] + sred[1][threadIdx.x] +
                  sred[2][threadIdx.x] + sred[3][threadIdx.x];
        atomicAdd(&out[threadIdx.x], s);
    }
}

extern "C" void kernel_launch(void* const* d_in, const int* in_sizes, int n_in,
                              void* d_out, int out_size, void* d_ws, size_t ws_size,
                              hipStream_t stream) {
    const float* imgs = (const float*)d_in[0];
    const float* z    = (const float*)d_in[1];
    float* out        = (float*)d_out;
    int npts = in_sizes[1] / 2;

    size_t ws_need = PART_OFF + (size_t)GB * 16 * sizeof(float);  // ~64.1 MB

    if (ws_size < ws_need) {
        int blocks = (npts + 255) / 256;
        zero_out_kernel<<<1, 64, 0, stream>>>(out);
        interp_grad_kernel<<<blocks, 256, 0, stream>>>(imgs, z, out, npts);
        return;
    }

    uint4* T        = (uint4*)d_ws;
    float* partials = (float*)((char*)d_ws + PART_OFF);

    precompute_kernel<<<NYX * 4, 256, 0, stream>>>(imgs, T);
    gather_kernel<<<GB, 256, 0, stream>>>(z, T, partials, npts);
    final_reduce_kernel<<<1, 256, 0, stream>>>(partials, out);
}